// Round 7
// baseline (660.854 us; speedup 1.0000x reference)
//
#include <hip/hip_runtime.h>
#include <hip/hip_bf16.h>

// 5-layer GCN: out = relu( D^-1/2 (A+I) D^-1/2 (x W_l) + b_l ), x5.
// N=50000, E=800000, D=128.
//
// R7 = R6 with compile fix: __builtin_nontemporal_store cannot take HIP
// class-type ushort4; split_x packs to native uint2 instead.
// R6 changes under test: non-temporal loads/stores on all streaming traffic
// so the agg kernel's XCD-pinned h-slice (3.2MB, slice = blockIdx&3 under
// presumed round-robin block->XCD dispatch) stays L2-resident:
//   - agg: nt edge-metadata loads, nt output stores; h gathers normal.
//   - gemm: nt x loads, nt h stores (protect W-fragment L2 reuse).
//   - fill/split_x: nt scatter/stream stores.
//   - dinv folded into scan_add (one fewer launch).

#define GCN_DIM 128

typedef short bf16x8 __attribute__((ext_vector_type(8)));
typedef float f32x4 __attribute__((ext_vector_type(4)));
typedef unsigned int u32x2 __attribute__((ext_vector_type(2)));

__device__ __forceinline__ unsigned short f2bf(float f) {
    unsigned int u = __float_as_uint(f);
    u += 0x7FFFu + ((u >> 16) & 1u);  // RTNE
    return (unsigned short)(u >> 16);
}
__device__ __forceinline__ float bf2f(unsigned short b) {
    return __uint_as_float(((unsigned int)b) << 16);
}
__device__ __forceinline__ float bflo(unsigned int p) { return __uint_as_float(p << 16); }
__device__ __forceinline__ float bfhi(unsigned int p) { return __uint_as_float(p & 0xFFFF0000u); }

__global__ void init_kernel(int* __restrict__ cnt, int n) {
    int i = blockIdx.x * 256 + threadIdx.x;
    if (i < n) cnt[i] = 0;
}

__global__ void count_kernel(const int* __restrict__ dst, int* __restrict__ cnt, int E) {
    int e = blockIdx.x * 256 + threadIdx.x;
    if (e < E) atomicAdd(&cnt[dst[e]], 1);
}

// ---- hierarchical scan ----
__global__ __launch_bounds__(256) void scan_part_kernel(const int* __restrict__ cnt,
                                                        int* __restrict__ loc,
                                                        int* __restrict__ bsum, int n) {
    __shared__ int s[256];
    int t = threadIdx.x;
    int i0 = blockIdx.x * 1024 + t * 4;
    int v0 = (i0 + 0 < n) ? cnt[i0 + 0] : 0;
    int v1 = (i0 + 1 < n) ? cnt[i0 + 1] : 0;
    int v2 = (i0 + 2 < n) ? cnt[i0 + 2] : 0;
    int v3 = (i0 + 3 < n) ? cnt[i0 + 3] : 0;
    int tsum = v0 + v1 + v2 + v3;
    s[t] = tsum;
    __syncthreads();
    for (int d = 1; d < 256; d <<= 1) {
        int u = (t >= d) ? s[t - d] : 0;
        __syncthreads();
        s[t] += u;
        __syncthreads();
    }
    int base = s[t] - tsum;
    if (i0 + 0 < n) loc[i0 + 0] = base; base += v0;
    if (i0 + 1 < n) loc[i0 + 1] = base; base += v1;
    if (i0 + 2 < n) loc[i0 + 2] = base; base += v2;
    if (i0 + 3 < n) loc[i0 + 3] = base;
    if (t == 255) bsum[blockIdx.x] = s[255];
}

__global__ __launch_bounds__(256) void scan_top_kernel(int* __restrict__ bsum, int nb) {
    __shared__ int s[256];
    int t = threadIdx.x;
    int v = (t < nb) ? bsum[t] : 0;
    s[t] = v;
    __syncthreads();
    for (int d = 1; d < 256; d <<= 1) {
        int u = (t >= d) ? s[t - d] : 0;
        __syncthreads();
        s[t] += u;
        __syncthreads();
    }
    if (t < nb) bsum[t] = s[t] - v;
}

// scan finalize + dinv (folded)
__global__ void scan_add_kernel(int* __restrict__ offs, int* __restrict__ cursor,
                                const int* __restrict__ bsum, const int* __restrict__ cnt,
                                float* __restrict__ dinv, int n, int E) {
    int i = blockIdx.x * 256 + threadIdx.x;
    if (i < n) {
        int off = offs[i] + bsum[i >> 10];
        offs[i] = off;
        cursor[i] = off;
        dinv[i] = rsqrtf((float)cnt[i] + 1.0f);
    }
    if (i == 0) offs[n] = E;
}

// CSR fill: packed (src, dinv[src]) as one 8B nt store.
__global__ void fill_kernel(const int* __restrict__ src, const int* __restrict__ dst,
                            const float* __restrict__ dinv, int* __restrict__ cursor,
                            long long* __restrict__ edat, int E) {
    int e = blockIdx.x * 256 + threadIdx.x;
    if (e < E) {
        int d = dst[e];
        int s = src[e];
        int p = atomicAdd(&cursor[d], 1);
        long long v = (long long)(unsigned int)s |
                      ((long long)__float_as_int(dinv[s]) << 32);
        __builtin_nontemporal_store(v, &edat[p]);
    }
}

// x0 fp32 -> (xh, xl) bf16 pair. nt (one-touch both sides); native-vector
// packed stores (builtin rejects HIP class types).
__global__ void split_x_kernel(const float* __restrict__ x, unsigned short* __restrict__ xh,
                               unsigned short* __restrict__ xl, int total) {
    int i = (blockIdx.x * 256 + threadIdx.x) * 4;
    if (i >= total) return;
    float4 v = *(const float4*)&x[i];
    unsigned short h0 = f2bf(v.x), h1 = f2bf(v.y), h2 = f2bf(v.z), h3 = f2bf(v.w);
    unsigned short l0 = f2bf(v.x - bf2f(h0)), l1 = f2bf(v.y - bf2f(h1));
    unsigned short l2 = f2bf(v.z - bf2f(h2)), l3 = f2bf(v.w - bf2f(h3));
    u32x2 hp, lp;
    hp.x = (unsigned int)h0 | ((unsigned int)h1 << 16);
    hp.y = (unsigned int)h2 | ((unsigned int)h3 << 16);
    lp.x = (unsigned int)l0 | ((unsigned int)l1 << 16);
    lp.y = (unsigned int)l2 | ((unsigned int)l3 << 16);
    __builtin_nontemporal_store(hp, (u32x2*)&xh[i]);
    __builtin_nontemporal_store(lp, (u32x2*)&xl[i]);
}

// W [l][k][n] fp32 -> Wfh/Wfl in MFMA B-fragment order:
// group g = l*32 + t*4 + ks; elem = ((g*64) + q*16+ln)*8 + j
// holds W^T[t*16+ln][ks*32+q*8+j].
__global__ void wsplit_kernel(const float* __restrict__ Wall, unsigned short* __restrict__ Wfh,
                              unsigned short* __restrict__ Wfl, int total) {
    int idx = blockIdx.x * 256 + threadIdx.x;
    if (idx >= total) return;
    int l = idx >> 14;
    int rem = idx & 16383;
    int k = rem >> 7;
    int nn = rem & 127;
    float v = Wall[idx];
    unsigned short hi = f2bf(v);
    unsigned short lo = f2bf(v - bf2f(hi));
    int t = nn >> 4, ln = nn & 15;
    int ks = k >> 5, q = (k >> 3) & 3, j = k & 7;
    int o = ((((l << 5) | (t << 2) | ks) << 6) | (q << 4) | ln) * 8 + j;
    Wfh[o] = hi;
    Wfl[o] = lo;
}

// MFMA GEMM: h = (xh+xl) @ (Wh+Wl), bf16 nt store. 128 rows/block, 4 waves.
// W hi+lo staged in 64KB LDS in fragment order. x loads nt (one-touch).
__global__ __launch_bounds__(256) void gemm_mfma_kernel(
    const unsigned short* __restrict__ xh, const unsigned short* __restrict__ xl,
    const unsigned short* __restrict__ Wfh, const unsigned short* __restrict__ Wfl,
    unsigned short* __restrict__ h, int n) {
    __shared__ unsigned short ldsW[2][16384];  // 32KB hi + 32KB lo
    int tid = threadIdx.x;
    {
        const uint4* gh = (const uint4*)Wfh;
        const uint4* gl = (const uint4*)Wfl;
        uint4* sh = (uint4*)ldsW[0];
        uint4* sl = (uint4*)ldsW[1];
#pragma unroll
        for (int r = 0; r < 8; r++) {
            sh[tid + 256 * r] = gh[tid + 256 * r];
            sl[tid + 256 * r] = gl[tid + 256 * r];
        }
    }
    int wave = tid >> 6, lane = tid & 63;
    int q = lane >> 4, ln = lane & 15;
    int rowbase = blockIdx.x * 128 + wave * 32;
    bf16x8 A[2][4][2];
#pragma unroll
    for (int m = 0; m < 2; m++) {
        int ar = rowbase + m * 16 + ln;
        if (ar >= n) ar = n - 1;
        size_t base = (size_t)ar * GCN_DIM;
#pragma unroll
        for (int ks = 0; ks < 4; ks++) {
            A[m][ks][0] = __builtin_nontemporal_load((const bf16x8*)&xh[base + ks * 32 + q * 8]);
            A[m][ks][1] = __builtin_nontemporal_load((const bf16x8*)&xl[base + ks * 32 + q * 8]);
        }
    }
    __syncthreads();
#pragma unroll
    for (int t = 0; t < 8; t++) {
        f32x4 acc0 = (f32x4)(0.f), acc1 = (f32x4)(0.f);
#pragma unroll
        for (int ks = 0; ks < 4; ks++) {
            int fo = ((t * 4 + ks) * 64 + lane) * 8;
            bf16x8 bh = *(const bf16x8*)&ldsW[0][fo];
            bf16x8 bl = *(const bf16x8*)&ldsW[1][fo];
            acc0 = __builtin_amdgcn_mfma_f32_16x16x32_bf16(A[0][ks][0], bh, acc0, 0, 0, 0);
            acc1 = __builtin_amdgcn_mfma_f32_16x16x32_bf16(A[1][ks][0], bh, acc1, 0, 0, 0);
            acc0 = __builtin_amdgcn_mfma_f32_16x16x32_bf16(A[0][ks][1], bh, acc0, 0, 0, 0);
            acc1 = __builtin_amdgcn_mfma_f32_16x16x32_bf16(A[1][ks][1], bh, acc1, 0, 0, 0);
            acc0 = __builtin_amdgcn_mfma_f32_16x16x32_bf16(A[0][ks][0], bl, acc0, 0, 0, 0);
            acc1 = __builtin_amdgcn_mfma_f32_16x16x32_bf16(A[1][ks][0], bl, acc1, 0, 0, 0);
        }
#pragma unroll
        for (int m = 0; m < 2; m++) {
            f32x4 a = m ? acc1 : acc0;
#pragma unroll
            for (int r = 0; r < 4; r++) {
                int row = rowbase + m * 16 + q * 4 + r;
                if (row < n)
                    __builtin_nontemporal_store(f2bf(a[r]), &h[(size_t)row * GCN_DIM + t * 16 + ln]);
            }
        }
    }
}

// Sliced aggregation: block = 16 nodes x one 32-feature slice
// (slice = blockIdx&3 -> XCD pair under round-robin dispatch; 3.2MB h-slice
// per XCD pair). nt metadata loads + nt output stores keep the slice
// L2-resident. Wave = 4 nodes x 16 lanes x 2 feats; unroll x4.
__global__ __launch_bounds__(256) void agg_kernel(
    const unsigned short* __restrict__ h,
    const long long* __restrict__ edat,
    const int* __restrict__ offs,
    const float* __restrict__ dinv, const float* __restrict__ bias,
    unsigned short* __restrict__ xh_out,
    unsigned short* __restrict__ xl_out,
    float* __restrict__ fout, int n) {
    int tid = threadIdx.x;
    int wave = tid >> 6, lane = tid & 63;
    int sub = lane >> 4, ln = lane & 15;
    int slice = blockIdx.x & 3;
    int node = (blockIdx.x >> 2) * 16 + wave * 4 + sub;
    if (node >= n) return;
    int co = slice * 32 + ln * 2;  // this lane's 2 features
    float di = dinv[node];
    unsigned int sp = *(const unsigned int*)&h[((size_t)node << 7) + co];
    float ax0 = di * bflo(sp);
    float ay0 = di * bfhi(sp);
    float ax1 = 0.f, ay1 = 0.f;
    int s = offs[node], e = offs[node + 1];
    int j = s;
    for (; j + 4 <= e; j += 4) {
        long long q0 = __builtin_nontemporal_load(&edat[j]);
        long long q1 = __builtin_nontemporal_load(&edat[j + 1]);
        long long q2 = __builtin_nontemporal_load(&edat[j + 2]);
        long long q3 = __builtin_nontemporal_load(&edat[j + 3]);
        int s0 = (int)(unsigned int)q0, s1 = (int)(unsigned int)q1;
        int s2 = (int)(unsigned int)q2, s3 = (int)(unsigned int)q3;
        float w0 = __int_as_float((int)(q0 >> 32));
        float w1 = __int_as_float((int)(q1 >> 32));
        float w2 = __int_as_float((int)(q2 >> 32));
        float w3 = __int_as_float((int)(q3 >> 32));
        unsigned int p0 = *(const unsigned int*)&h[((size_t)s0 << 7) + co];
        unsigned int p1 = *(const unsigned int*)&h[((size_t)s1 << 7) + co];
        unsigned int p2 = *(const unsigned int*)&h[((size_t)s2 << 7) + co];
        unsigned int p3 = *(const unsigned int*)&h[((size_t)s3 << 7) + co];
        ax0 = fmaf(w0, bflo(p0), ax0); ay0 = fmaf(w0, bfhi(p0), ay0);
        ax1 = fmaf(w1, bflo(p1), ax1); ay1 = fmaf(w1, bfhi(p1), ay1);
        ax0 = fmaf(w2, bflo(p2), ax0); ay0 = fmaf(w2, bfhi(p2), ay0);
        ax1 = fmaf(w3, bflo(p3), ax1); ay1 = fmaf(w3, bfhi(p3), ay1);
    }
    for (; j < e; j++) {
        long long q0 = __builtin_nontemporal_load(&edat[j]);
        int s0 = (int)(unsigned int)q0;
        float w0 = __int_as_float((int)(q0 >> 32));
        unsigned int p0 = *(const unsigned int*)&h[((size_t)s0 << 7) + co];
        ax0 = fmaf(w0, bflo(p0), ax0);
        ay0 = fmaf(w0, bfhi(p0), ay0);
    }
    float ax = ax0 + ax1, ay = ay0 + ay1;
    float2 b = *(const float2*)&bias[co];
    float rx = fmaxf(fmaf(di, ax, b.x), 0.f);
    float ry = fmaxf(fmaf(di, ay, b.y), 0.f);
    if (fout) {
        unsigned long long pv = (unsigned long long)__float_as_uint(rx) |
                                ((unsigned long long)__float_as_uint(ry) << 32);
        __builtin_nontemporal_store(pv, (unsigned long long*)&fout[((size_t)node << 7) + co]);
    } else {
        unsigned short hx = f2bf(rx), hy = f2bf(ry);
        unsigned int hp = (unsigned int)hx | ((unsigned int)hy << 16);
        unsigned short lx = f2bf(rx - bf2f(hx)), ly = f2bf(ry - bf2f(hy));
        unsigned int lp = (unsigned int)lx | ((unsigned int)ly << 16);
        __builtin_nontemporal_store(hp, (unsigned int*)&xh_out[((size_t)node << 7) + co]);
        __builtin_nontemporal_store(lp, (unsigned int*)&xl_out[((size_t)node << 7) + co]);
    }
}

extern "C" void kernel_launch(void* const* d_in, const int* in_sizes, int n_in,
                              void* d_out, int out_size, void* d_ws, size_t ws_size,
                              hipStream_t stream) {
    const float* x0    = (const float*)d_in[0];
    const int*   edges = (const int*)d_in[1];   // [2, E] int32: src then dst
    const float* Wall  = (const float*)d_in[2]; // [L, 128, 128]
    const float* Ball  = (const float*)d_in[3]; // [L, 128]
    float* out = (float*)d_out;

    const int n = in_sizes[0] / GCN_DIM;              // 50000
    const int E = in_sizes[1] / 2;                    // 800000
    const int L = in_sizes[2] / (GCN_DIM * GCN_DIM);  // 5

    // workspace layout
    int*   cnt    = (int*)d_ws;                        // n
    float* dinv   = (float*)(cnt + n);                 // n
    int*   offs   = (int*)(dinv + n);                  // n+16
    int*   cursor = offs + n + 16;                     // n
    int*   bsum   = cursor + n;                        // 64 (+ pad to 8B align)
    long long* edat = (long long*)(bsum + 64);         // E (8B each, 8B-aligned)
    unsigned short* h   = (unsigned short*)(edat + E); // n*128 bf16
    unsigned short* xh  = h  + (size_t)n * GCN_DIM;    // n*128 bf16
    unsigned short* xl  = xh + (size_t)n * GCN_DIM;    // n*128 bf16
    unsigned short* Wfh = xl + (size_t)n * GCN_DIM;    // L*16384 bf16 frag-order
    unsigned short* Wfl = Wfh + (size_t)L * GCN_DIM * GCN_DIM;

    const int* src = edges;
    const int* dst = edges + E;

    int nb_n = (n + 255) / 256;
    int nb_e = (E + 255) / 256;
    int nb_scan = (n + 1023) / 1024;

    init_kernel<<<nb_n, 256, 0, stream>>>(cnt, n);
    count_kernel<<<nb_e, 256, 0, stream>>>(dst, cnt, E);
    scan_part_kernel<<<nb_scan, 256, 0, stream>>>(cnt, offs, bsum, n);
    scan_top_kernel<<<1, 256, 0, stream>>>(bsum, nb_scan);
    scan_add_kernel<<<nb_n, 256, 0, stream>>>(offs, cursor, bsum, cnt, dinv, n, E);
    fill_kernel<<<nb_e, 256, 0, stream>>>(src, dst, dinv, cursor, edat, E);

    int xtotal = n * GCN_DIM;
    split_x_kernel<<<(xtotal / 4 + 255) / 256, 256, 0, stream>>>(x0, xh, xl, xtotal);
    int wtotal = L * GCN_DIM * GCN_DIM;
    wsplit_kernel<<<(wtotal + 255) / 256, 256, 0, stream>>>(Wall, Wfh, Wfl, wtotal);

    int gemm_blocks = (n + 127) / 128;
    int agg_blocks  = ((n + 15) / 16) * 4;  // 16 nodes x 4 slices per block

    for (int l = 0; l < L; l++) {
        gemm_mfma_kernel<<<gemm_blocks, 256, 0, stream>>>(
            xh, xl, Wfh + (size_t)l * GCN_DIM * GCN_DIM, Wfl + (size_t)l * GCN_DIM * GCN_DIM, h, n);
        agg_kernel<<<agg_blocks, 256, 0, stream>>>(
            h, edat, offs, dinv, Ball + (size_t)l * GCN_DIM,
            xh, xl, (l == L - 1) ? out : nullptr, n);
    }
}

// Round 8
// 478.067 us; speedup vs baseline: 1.3823x; 1.3823x over previous
//
#include <hip/hip_runtime.h>
#include <hip/hip_bf16.h>

// 5-layer GCN: out = relu( D^-1/2 (A+I) D^-1/2 (x W_l) + b_l ), x5.
// N=50000, E=800000, D=128.
//
// R8: revert ALL non-temporal hints (R7 lesson: nt stores on h evicted it
// from L2 and agg's gathers went cold, +25MB FETCH, +28us/dispatch).
// New: (1) edat packed to 4B = src(16b) | deg(16b); agg recomputes
//          w = rsqrtf(deg+1) (bit-identical to dinv[src]).
//      (2) agg edge loop unroll x8, 4 accumulator pairs (8 gathers in
//          flight; deg~16 -> 2 iterations).
//      (3) gemm stages W in two 32KB halves instead of one 64KB block
//          -> 5 blocks/CU instead of 2 (hide A-load/store latency).

#define GCN_DIM 128

typedef short bf16x8 __attribute__((ext_vector_type(8)));
typedef float f32x4 __attribute__((ext_vector_type(4)));

__device__ __forceinline__ unsigned short f2bf(float f) {
    unsigned int u = __float_as_uint(f);
    u += 0x7FFFu + ((u >> 16) & 1u);  // RTNE
    return (unsigned short)(u >> 16);
}
__device__ __forceinline__ float bf2f(unsigned short b) {
    return __uint_as_float(((unsigned int)b) << 16);
}
__device__ __forceinline__ float bflo(unsigned int p) { return __uint_as_float(p << 16); }
__device__ __forceinline__ float bfhi(unsigned int p) { return __uint_as_float(p & 0xFFFF0000u); }

__global__ void init_kernel(int* __restrict__ cnt, int n) {
    int i = blockIdx.x * 256 + threadIdx.x;
    if (i < n) cnt[i] = 0;
}

__global__ void count_kernel(const int* __restrict__ dst, int* __restrict__ cnt, int E) {
    int e = blockIdx.x * 256 + threadIdx.x;
    if (e < E) atomicAdd(&cnt[dst[e]], 1);
}

// ---- hierarchical scan ----
__global__ __launch_bounds__(256) void scan_part_kernel(const int* __restrict__ cnt,
                                                        int* __restrict__ loc,
                                                        int* __restrict__ bsum, int n) {
    __shared__ int s[256];
    int t = threadIdx.x;
    int i0 = blockIdx.x * 1024 + t * 4;
    int v0 = (i0 + 0 < n) ? cnt[i0 + 0] : 0;
    int v1 = (i0 + 1 < n) ? cnt[i0 + 1] : 0;
    int v2 = (i0 + 2 < n) ? cnt[i0 + 2] : 0;
    int v3 = (i0 + 3 < n) ? cnt[i0 + 3] : 0;
    int tsum = v0 + v1 + v2 + v3;
    s[t] = tsum;
    __syncthreads();
    for (int d = 1; d < 256; d <<= 1) {
        int u = (t >= d) ? s[t - d] : 0;
        __syncthreads();
        s[t] += u;
        __syncthreads();
    }
    int base = s[t] - tsum;
    if (i0 + 0 < n) loc[i0 + 0] = base; base += v0;
    if (i0 + 1 < n) loc[i0 + 1] = base; base += v1;
    if (i0 + 2 < n) loc[i0 + 2] = base; base += v2;
    if (i0 + 3 < n) loc[i0 + 3] = base;
    if (t == 255) bsum[blockIdx.x] = s[255];
}

__global__ __launch_bounds__(256) void scan_top_kernel(int* __restrict__ bsum, int nb) {
    __shared__ int s[256];
    int t = threadIdx.x;
    int v = (t < nb) ? bsum[t] : 0;
    s[t] = v;
    __syncthreads();
    for (int d = 1; d < 256; d <<= 1) {
        int u = (t >= d) ? s[t - d] : 0;
        __syncthreads();
        s[t] += u;
        __syncthreads();
    }
    if (t < nb) bsum[t] = s[t] - v;
}

// scan finalize + dinv (folded)
__global__ void scan_add_kernel(int* __restrict__ offs, int* __restrict__ cursor,
                                const int* __restrict__ bsum, const int* __restrict__ cnt,
                                float* __restrict__ dinv, int n, int E) {
    int i = blockIdx.x * 256 + threadIdx.x;
    if (i < n) {
        int off = offs[i] + bsum[i >> 10];
        offs[i] = off;
        cursor[i] = off;
        dinv[i] = rsqrtf((float)cnt[i] + 1.0f);
    }
    if (i == 0) offs[n] = E;
}

// CSR fill: packed (src | deg[src]<<16) 4B stores (src < 65536, deg < 65536).
__global__ void fill_kernel(const int* __restrict__ src, const int* __restrict__ dst,
                            const int* __restrict__ cnt, int* __restrict__ cursor,
                            unsigned int* __restrict__ edat, int E) {
    int e = blockIdx.x * 256 + threadIdx.x;
    if (e < E) {
        int d = dst[e];
        int s = src[e];
        int p = atomicAdd(&cursor[d], 1);
        edat[p] = (unsigned int)s | ((unsigned int)cnt[s] << 16);
    }
}

// x0 fp32 -> (xh, xl) bf16 pair.
__global__ void split_x_kernel(const float* __restrict__ x, unsigned short* __restrict__ xh,
                               unsigned short* __restrict__ xl, int total) {
    int i = (blockIdx.x * 256 + threadIdx.x) * 4;
    if (i >= total) return;
    float4 v = *(const float4*)&x[i];
    ushort4 h4, l4;
    h4.x = f2bf(v.x); l4.x = f2bf(v.x - bf2f(h4.x));
    h4.y = f2bf(v.y); l4.y = f2bf(v.y - bf2f(h4.y));
    h4.z = f2bf(v.z); l4.z = f2bf(v.z - bf2f(h4.z));
    h4.w = f2bf(v.w); l4.w = f2bf(v.w - bf2f(h4.w));
    *(ushort4*)&xh[i] = h4;
    *(ushort4*)&xl[i] = l4;
}

// W [l][k][n] fp32 -> Wfh/Wfl in MFMA B-fragment order:
// group g = l*32 + t*4 + ks; elem = ((g*64) + q*16+ln)*8 + j
// holds W^T[t*16+ln][ks*32+q*8+j].
__global__ void wsplit_kernel(const float* __restrict__ Wall, unsigned short* __restrict__ Wfh,
                              unsigned short* __restrict__ Wfl, int total) {
    int idx = blockIdx.x * 256 + threadIdx.x;
    if (idx >= total) return;
    int l = idx >> 14;
    int rem = idx & 16383;
    int k = rem >> 7;
    int nn = rem & 127;
    float v = Wall[idx];
    unsigned short hi = f2bf(v);
    unsigned short lo = f2bf(v - bf2f(hi));
    int t = nn >> 4, ln = nn & 15;
    int ks = k >> 5, q = (k >> 3) & 3, j = k & 7;
    int o = ((((l << 5) | (t << 2) | ks) << 6) | (q << 4) | ln) * 8 + j;
    Wfh[o] = hi;
    Wfl[o] = lo;
}

// MFMA GEMM: h = (xh+xl) @ (Wh+Wl), bf16 store. 128 rows/block, 4 waves.
// W staged in TWO 32KB halves (16KB hi + 16KB lo each) -> 5 blocks/CU.
__global__ __launch_bounds__(256) void gemm_mfma_kernel(
    const unsigned short* __restrict__ xh, const unsigned short* __restrict__ xl,
    const unsigned short* __restrict__ Wfh, const unsigned short* __restrict__ Wfl,
    unsigned short* __restrict__ h, int n) {
    __shared__ unsigned short ldsW[2][8192];  // 16KB hi + 16KB lo
    int tid = threadIdx.x;
    int wave = tid >> 6, lane = tid & 63;
    int q = lane >> 4, ln = lane & 15;
    int rowbase = blockIdx.x * 128 + wave * 32;
    bf16x8 A[2][4][2];
#pragma unroll
    for (int m = 0; m < 2; m++) {
        int ar = rowbase + m * 16 + ln;
        if (ar >= n) ar = n - 1;
        size_t base = (size_t)ar * GCN_DIM;
#pragma unroll
        for (int ks = 0; ks < 4; ks++) {
            A[m][ks][0] = *(const bf16x8*)&xh[base + ks * 32 + q * 8];
            A[m][ks][1] = *(const bf16x8*)&xl[base + ks * 32 + q * 8];
        }
    }
#pragma unroll
    for (int half = 0; half < 2; half++) {
        if (half) __syncthreads();  // wait for previous half's compute
        {
            const uint4* gh = (const uint4*)(Wfh + half * 8192);
            const uint4* gl = (const uint4*)(Wfl + half * 8192);
            uint4* sh = (uint4*)ldsW[0];
            uint4* sl = (uint4*)ldsW[1];
#pragma unroll
            for (int r = 0; r < 4; r++) {
                sh[tid + 256 * r] = gh[tid + 256 * r];
                sl[tid + 256 * r] = gl[tid + 256 * r];
            }
        }
        __syncthreads();
#pragma unroll
        for (int tt = 0; tt < 4; tt++) {
            int t = half * 4 + tt;
            f32x4 acc0 = (f32x4)(0.f), acc1 = (f32x4)(0.f);
#pragma unroll
            for (int ks = 0; ks < 4; ks++) {
                int fo = ((tt * 4 + ks) * 64 + lane) * 8;
                bf16x8 bh = *(const bf16x8*)&ldsW[0][fo];
                bf16x8 bl = *(const bf16x8*)&ldsW[1][fo];
                acc0 = __builtin_amdgcn_mfma_f32_16x16x32_bf16(A[0][ks][0], bh, acc0, 0, 0, 0);
                acc1 = __builtin_amdgcn_mfma_f32_16x16x32_bf16(A[1][ks][0], bh, acc1, 0, 0, 0);
                acc0 = __builtin_amdgcn_mfma_f32_16x16x32_bf16(A[0][ks][1], bh, acc0, 0, 0, 0);
                acc1 = __builtin_amdgcn_mfma_f32_16x16x32_bf16(A[1][ks][1], bh, acc1, 0, 0, 0);
                acc0 = __builtin_amdgcn_mfma_f32_16x16x32_bf16(A[0][ks][0], bl, acc0, 0, 0, 0);
                acc1 = __builtin_amdgcn_mfma_f32_16x16x32_bf16(A[1][ks][0], bl, acc1, 0, 0, 0);
            }
#pragma unroll
            for (int m = 0; m < 2; m++) {
                f32x4 a = m ? acc1 : acc0;
#pragma unroll
                for (int r = 0; r < 4; r++) {
                    int row = rowbase + m * 16 + q * 4 + r;
                    if (row < n) h[(size_t)row * GCN_DIM + t * 16 + ln] = f2bf(a[r]);
                }
            }
        }
    }
}

// Sliced aggregation: block = 16 nodes x one 32-feature slice (slice =
// blockIdx&3). Wave = 4 nodes x 16 lanes x 2 feats. Unroll x8, 4 acc pairs.
// Edge meta: 4B packed (src | deg<<16); w = rsqrtf(deg+1) == dinv[src].
__global__ __launch_bounds__(256) void agg_kernel(
    const unsigned short* __restrict__ h,
    const unsigned int* __restrict__ edat,
    const int* __restrict__ offs,
    const float* __restrict__ dinv, const float* __restrict__ bias,
    unsigned short* __restrict__ xh_out,
    unsigned short* __restrict__ xl_out,
    float* __restrict__ fout, int n) {
    int tid = threadIdx.x;
    int wave = tid >> 6, lane = tid & 63;
    int sub = lane >> 4, ln = lane & 15;
    int slice = blockIdx.x & 3;
    int node = (blockIdx.x >> 2) * 16 + wave * 4 + sub;
    if (node >= n) return;
    int co = slice * 32 + ln * 2;  // this lane's 2 features
    float di = dinv[node];
    unsigned int sp = *(const unsigned int*)&h[((size_t)node << 7) + co];
    float ax0 = di * bflo(sp), ay0 = di * bfhi(sp);
    float ax1 = 0.f, ay1 = 0.f, ax2 = 0.f, ay2 = 0.f, ax3 = 0.f, ay3 = 0.f;
    int s = offs[node], e = offs[node + 1];
    int j = s;
    for (; j + 8 <= e; j += 8) {
        unsigned int v0 = edat[j], v1 = edat[j + 1], v2 = edat[j + 2], v3 = edat[j + 3];
        unsigned int v4 = edat[j + 4], v5 = edat[j + 5], v6 = edat[j + 6], v7 = edat[j + 7];
        unsigned int p0 = *(const unsigned int*)&h[((size_t)(v0 & 0xFFFFu) << 7) + co];
        unsigned int p1 = *(const unsigned int*)&h[((size_t)(v1 & 0xFFFFu) << 7) + co];
        unsigned int p2 = *(const unsigned int*)&h[((size_t)(v2 & 0xFFFFu) << 7) + co];
        unsigned int p3 = *(const unsigned int*)&h[((size_t)(v3 & 0xFFFFu) << 7) + co];
        unsigned int p4 = *(const unsigned int*)&h[((size_t)(v4 & 0xFFFFu) << 7) + co];
        unsigned int p5 = *(const unsigned int*)&h[((size_t)(v5 & 0xFFFFu) << 7) + co];
        unsigned int p6 = *(const unsigned int*)&h[((size_t)(v6 & 0xFFFFu) << 7) + co];
        unsigned int p7 = *(const unsigned int*)&h[((size_t)(v7 & 0xFFFFu) << 7) + co];
        float w0 = rsqrtf((float)(v0 >> 16) + 1.0f);
        float w1 = rsqrtf((float)(v1 >> 16) + 1.0f);
        float w2 = rsqrtf((float)(v2 >> 16) + 1.0f);
        float w3 = rsqrtf((float)(v3 >> 16) + 1.0f);
        float w4 = rsqrtf((float)(v4 >> 16) + 1.0f);
        float w5 = rsqrtf((float)(v5 >> 16) + 1.0f);
        float w6 = rsqrtf((float)(v6 >> 16) + 1.0f);
        float w7 = rsqrtf((float)(v7 >> 16) + 1.0f);
        ax0 = fmaf(w0, bflo(p0), ax0); ay0 = fmaf(w0, bfhi(p0), ay0);
        ax1 = fmaf(w1, bflo(p1), ax1); ay1 = fmaf(w1, bfhi(p1), ay1);
        ax2 = fmaf(w2, bflo(p2), ax2); ay2 = fmaf(w2, bfhi(p2), ay2);
        ax3 = fmaf(w3, bflo(p3), ax3); ay3 = fmaf(w3, bfhi(p3), ay3);
        ax0 = fmaf(w4, bflo(p4), ax0); ay0 = fmaf(w4, bfhi(p4), ay0);
        ax1 = fmaf(w5, bflo(p5), ax1); ay1 = fmaf(w5, bfhi(p5), ay1);
        ax2 = fmaf(w6, bflo(p6), ax2); ay2 = fmaf(w6, bfhi(p6), ay2);
        ax3 = fmaf(w7, bflo(p7), ax3); ay3 = fmaf(w7, bfhi(p7), ay3);
    }
    for (; j + 4 <= e; j += 4) {
        unsigned int v0 = edat[j], v1 = edat[j + 1], v2 = edat[j + 2], v3 = edat[j + 3];
        unsigned int p0 = *(const unsigned int*)&h[((size_t)(v0 & 0xFFFFu) << 7) + co];
        unsigned int p1 = *(const unsigned int*)&h[((size_t)(v1 & 0xFFFFu) << 7) + co];
        unsigned int p2 = *(const unsigned int*)&h[((size_t)(v2 & 0xFFFFu) << 7) + co];
        unsigned int p3 = *(const unsigned int*)&h[((size_t)(v3 & 0xFFFFu) << 7) + co];
        float w0 = rsqrtf((float)(v0 >> 16) + 1.0f);
        float w1 = rsqrtf((float)(v1 >> 16) + 1.0f);
        float w2 = rsqrtf((float)(v2 >> 16) + 1.0f);
        float w3 = rsqrtf((float)(v3 >> 16) + 1.0f);
        ax0 = fmaf(w0, bflo(p0), ax0); ay0 = fmaf(w0, bfhi(p0), ay0);
        ax1 = fmaf(w1, bflo(p1), ax1); ay1 = fmaf(w1, bfhi(p1), ay1);
        ax2 = fmaf(w2, bflo(p2), ax2); ay2 = fmaf(w2, bfhi(p2), ay2);
        ax3 = fmaf(w3, bflo(p3), ax3); ay3 = fmaf(w3, bfhi(p3), ay3);
    }
    for (; j < e; j++) {
        unsigned int v0 = edat[j];
        unsigned int p0 = *(const unsigned int*)&h[((size_t)(v0 & 0xFFFFu) << 7) + co];
        float w0 = rsqrtf((float)(v0 >> 16) + 1.0f);
        ax0 = fmaf(w0, bflo(p0), ax0);
        ay0 = fmaf(w0, bfhi(p0), ay0);
    }
    float ax = (ax0 + ax1) + (ax2 + ax3);
    float ay = (ay0 + ay1) + (ay2 + ay3);
    float2 b = *(const float2*)&bias[co];
    float rx = fmaxf(fmaf(di, ax, b.x), 0.f);
    float ry = fmaxf(fmaf(di, ay, b.y), 0.f);
    if (fout) {
        *(float2*)&fout[((size_t)node << 7) + co] = make_float2(rx, ry);
    } else {
        ushort2 hh, ll;
        hh.x = f2bf(rx); ll.x = f2bf(rx - bf2f(hh.x));
        hh.y = f2bf(ry); ll.y = f2bf(ry - bf2f(hh.y));
        *(ushort2*)&xh_out[((size_t)node << 7) + co] = hh;
        *(ushort2*)&xl_out[((size_t)node << 7) + co] = ll;
    }
}

extern "C" void kernel_launch(void* const* d_in, const int* in_sizes, int n_in,
                              void* d_out, int out_size, void* d_ws, size_t ws_size,
                              hipStream_t stream) {
    const float* x0    = (const float*)d_in[0];
    const int*   edges = (const int*)d_in[1];   // [2, E] int32: src then dst
    const float* Wall  = (const float*)d_in[2]; // [L, 128, 128]
    const float* Ball  = (const float*)d_in[3]; // [L, 128]
    float* out = (float*)d_out;

    const int n = in_sizes[0] / GCN_DIM;              // 50000
    const int E = in_sizes[1] / 2;                    // 800000
    const int L = in_sizes[2] / (GCN_DIM * GCN_DIM);  // 5

    // workspace layout
    int*   cnt    = (int*)d_ws;                        // n
    float* dinv   = (float*)(cnt + n);                 // n
    int*   offs   = (int*)(dinv + n);                  // n+16
    int*   cursor = offs + n + 16;                     // n
    int*   bsum   = cursor + n;                        // 64
    unsigned int* edat = (unsigned int*)(bsum + 64);   // E (4B each)
    unsigned short* h   = (unsigned short*)(edat + E); // n*128 bf16
    unsigned short* xh  = h  + (size_t)n * GCN_DIM;    // n*128 bf16
    unsigned short* xl  = xh + (size_t)n * GCN_DIM;    // n*128 bf16
    unsigned short* Wfh = xl + (size_t)n * GCN_DIM;    // L*16384 bf16 frag-order
    unsigned short* Wfl = Wfh + (size_t)L * GCN_DIM * GCN_DIM;

    const int* src = edges;
    const int* dst = edges + E;

    int nb_n = (n + 255) / 256;
    int nb_e = (E + 255) / 256;
    int nb_scan = (n + 1023) / 1024;

    init_kernel<<<nb_n, 256, 0, stream>>>(cnt, n);
    count_kernel<<<nb_e, 256, 0, stream>>>(dst, cnt, E);
    scan_part_kernel<<<nb_scan, 256, 0, stream>>>(cnt, offs, bsum, n);
    scan_top_kernel<<<1, 256, 0, stream>>>(bsum, nb_scan);
    scan_add_kernel<<<nb_n, 256, 0, stream>>>(offs, cursor, bsum, cnt, dinv, n, E);
    fill_kernel<<<nb_e, 256, 0, stream>>>(src, dst, cnt, cursor, edat, E);

    int xtotal = n * GCN_DIM;
    split_x_kernel<<<(xtotal / 4 + 255) / 256, 256, 0, stream>>>(x0, xh, xl, xtotal);
    int wtotal = L * GCN_DIM * GCN_DIM;
    wsplit_kernel<<<(wtotal + 255) / 256, 256, 0, stream>>>(Wall, Wfh, Wfl, wtotal);

    int gemm_blocks = (n + 127) / 128;
    int agg_blocks  = ((n + 15) / 16) * 4;  // 16 nodes x 4 slices per block

    for (int l = 0; l < L; l++) {
        gemm_mfma_kernel<<<gemm_blocks, 256, 0, stream>>>(
            xh, xl, Wfh + (size_t)l * GCN_DIM * GCN_DIM, Wfl + (size_t)l * GCN_DIM * GCN_DIM, h, n);
        agg_kernel<<<agg_blocks, 256, 0, stream>>>(
            h, edat, offs, dinv, Ball + (size_t)l * GCN_DIM,
            xh, xl, (l == L - 1) ? out : nullptr, n);
    }
}

// Round 9
// 439.419 us; speedup vs baseline: 1.5039x; 1.0880x over previous
//
#include <hip/hip_runtime.h>
#include <hip/hip_bf16.h>

// 5-layer GCN: out = relu( D^-1/2 (A+I) D^-1/2 (x W_l) + b_l ), x5.
// N=50000, E=800000, D=128.
//
// R9: (1) nt stores ONLY on agg outputs (xh/xl/fout). Theory: per-XCD L2
//     holds the 3.2MB h-slice, but agg's own output write-allocations evict
//     it; outputs have ~no L2 reuse value (consumed next layer by gemm on a
//     different XCD 7/8 of the time). R7's global-nt failure conflated this
//     with nt'ing gemm h-stores (killed agg's source) + edat loads.
//     (2) fill without atomics: count_kernel saves rank[e] (its atomicAdd
//     return, coalesced); fill computes p = offs[dst]+rank[e]. Cursor gone.
//     (3) gemm/agg structure frozen at R8.

#define GCN_DIM 128

typedef short bf16x8 __attribute__((ext_vector_type(8)));
typedef float f32x4 __attribute__((ext_vector_type(4)));

__device__ __forceinline__ unsigned short f2bf(float f) {
    unsigned int u = __float_as_uint(f);
    u += 0x7FFFu + ((u >> 16) & 1u);  // RTNE
    return (unsigned short)(u >> 16);
}
__device__ __forceinline__ float bf2f(unsigned short b) {
    return __uint_as_float(((unsigned int)b) << 16);
}
__device__ __forceinline__ float bflo(unsigned int p) { return __uint_as_float(p << 16); }
__device__ __forceinline__ float bfhi(unsigned int p) { return __uint_as_float(p & 0xFFFF0000u); }

__global__ void init_kernel(int* __restrict__ cnt, int n) {
    int i = blockIdx.x * 256 + threadIdx.x;
    if (i < n) cnt[i] = 0;
}

// count + capture per-edge rank (old value of the atomic)
__global__ void count_kernel(const int* __restrict__ dst, int* __restrict__ cnt,
                             int* __restrict__ rank, int E) {
    int e = blockIdx.x * 256 + threadIdx.x;
    if (e < E) rank[e] = atomicAdd(&cnt[dst[e]], 1);
}

// ---- hierarchical scan ----
__global__ __launch_bounds__(256) void scan_part_kernel(const int* __restrict__ cnt,
                                                        int* __restrict__ loc,
                                                        int* __restrict__ bsum, int n) {
    __shared__ int s[256];
    int t = threadIdx.x;
    int i0 = blockIdx.x * 1024 + t * 4;
    int v0 = (i0 + 0 < n) ? cnt[i0 + 0] : 0;
    int v1 = (i0 + 1 < n) ? cnt[i0 + 1] : 0;
    int v2 = (i0 + 2 < n) ? cnt[i0 + 2] : 0;
    int v3 = (i0 + 3 < n) ? cnt[i0 + 3] : 0;
    int tsum = v0 + v1 + v2 + v3;
    s[t] = tsum;
    __syncthreads();
    for (int d = 1; d < 256; d <<= 1) {
        int u = (t >= d) ? s[t - d] : 0;
        __syncthreads();
        s[t] += u;
        __syncthreads();
    }
    int base = s[t] - tsum;
    if (i0 + 0 < n) loc[i0 + 0] = base; base += v0;
    if (i0 + 1 < n) loc[i0 + 1] = base; base += v1;
    if (i0 + 2 < n) loc[i0 + 2] = base; base += v2;
    if (i0 + 3 < n) loc[i0 + 3] = base;
    if (t == 255) bsum[blockIdx.x] = s[255];
}

__global__ __launch_bounds__(256) void scan_top_kernel(int* __restrict__ bsum, int nb) {
    __shared__ int s[256];
    int t = threadIdx.x;
    int v = (t < nb) ? bsum[t] : 0;
    s[t] = v;
    __syncthreads();
    for (int d = 1; d < 256; d <<= 1) {
        int u = (t >= d) ? s[t - d] : 0;
        __syncthreads();
        s[t] += u;
        __syncthreads();
    }
    if (t < nb) bsum[t] = s[t] - v;
}

// scan finalize + dinv (folded)
__global__ void scan_add_kernel(int* __restrict__ offs,
                                const int* __restrict__ bsum, const int* __restrict__ cnt,
                                float* __restrict__ dinv, int n, int E) {
    int i = blockIdx.x * 256 + threadIdx.x;
    if (i < n) {
        offs[i] = offs[i] + bsum[i >> 10];
        dinv[i] = rsqrtf((float)cnt[i] + 1.0f);
    }
    if (i == 0) offs[n] = E;
}

// CSR fill, atomic-free: p = offs[dst] + rank[e]. Packed (src | deg<<16).
__global__ void fill_kernel(const int* __restrict__ src, const int* __restrict__ dst,
                            const int* __restrict__ cnt, const int* __restrict__ rank,
                            const int* __restrict__ offs,
                            unsigned int* __restrict__ edat, int E) {
    int e = blockIdx.x * 256 + threadIdx.x;
    if (e < E) {
        int d = dst[e];
        int s = src[e];
        int p = offs[d] + rank[e];
        edat[p] = (unsigned int)s | ((unsigned int)cnt[s] << 16);
    }
}

// x0 fp32 -> (xh, xl) bf16 pair.
__global__ void split_x_kernel(const float* __restrict__ x, unsigned short* __restrict__ xh,
                               unsigned short* __restrict__ xl, int total) {
    int i = (blockIdx.x * 256 + threadIdx.x) * 4;
    if (i >= total) return;
    float4 v = *(const float4*)&x[i];
    ushort4 h4, l4;
    h4.x = f2bf(v.x); l4.x = f2bf(v.x - bf2f(h4.x));
    h4.y = f2bf(v.y); l4.y = f2bf(v.y - bf2f(h4.y));
    h4.z = f2bf(v.z); l4.z = f2bf(v.z - bf2f(h4.z));
    h4.w = f2bf(v.w); l4.w = f2bf(v.w - bf2f(h4.w));
    *(ushort4*)&xh[i] = h4;
    *(ushort4*)&xl[i] = l4;
}

// W [l][k][n] fp32 -> Wfh/Wfl in MFMA B-fragment order:
// group g = l*32 + t*4 + ks; elem = ((g*64) + q*16+ln)*8 + j
// holds W^T[t*16+ln][ks*32+q*8+j].
__global__ void wsplit_kernel(const float* __restrict__ Wall, unsigned short* __restrict__ Wfh,
                              unsigned short* __restrict__ Wfl, int total) {
    int idx = blockIdx.x * 256 + threadIdx.x;
    if (idx >= total) return;
    int l = idx >> 14;
    int rem = idx & 16383;
    int k = rem >> 7;
    int nn = rem & 127;
    float v = Wall[idx];
    unsigned short hi = f2bf(v);
    unsigned short lo = f2bf(v - bf2f(hi));
    int t = nn >> 4, ln = nn & 15;
    int ks = k >> 5, q = (k >> 3) & 3, j = k & 7;
    int o = ((((l << 5) | (t << 2) | ks) << 6) | (q << 4) | ln) * 8 + j;
    Wfh[o] = hi;
    Wfl[o] = lo;
}

// MFMA GEMM: h = (xh+xl) @ (Wh+Wl), bf16 store. 128 rows/block, 4 waves.
// W staged in TWO 32KB halves (16KB hi + 16KB lo each) -> 5 blocks/CU.
__global__ __launch_bounds__(256) void gemm_mfma_kernel(
    const unsigned short* __restrict__ xh, const unsigned short* __restrict__ xl,
    const unsigned short* __restrict__ Wfh, const unsigned short* __restrict__ Wfl,
    unsigned short* __restrict__ h, int n) {
    __shared__ unsigned short ldsW[2][8192];  // 16KB hi + 16KB lo
    int tid = threadIdx.x;
    int wave = tid >> 6, lane = tid & 63;
    int q = lane >> 4, ln = lane & 15;
    int rowbase = blockIdx.x * 128 + wave * 32;
    bf16x8 A[2][4][2];
#pragma unroll
    for (int m = 0; m < 2; m++) {
        int ar = rowbase + m * 16 + ln;
        if (ar >= n) ar = n - 1;
        size_t base = (size_t)ar * GCN_DIM;
#pragma unroll
        for (int ks = 0; ks < 4; ks++) {
            A[m][ks][0] = *(const bf16x8*)&xh[base + ks * 32 + q * 8];
            A[m][ks][1] = *(const bf16x8*)&xl[base + ks * 32 + q * 8];
        }
    }
#pragma unroll
    for (int half = 0; half < 2; half++) {
        if (half) __syncthreads();  // wait for previous half's compute
        {
            const uint4* gh = (const uint4*)(Wfh + half * 8192);
            const uint4* gl = (const uint4*)(Wfl + half * 8192);
            uint4* sh = (uint4*)ldsW[0];
            uint4* sl = (uint4*)ldsW[1];
#pragma unroll
            for (int r = 0; r < 4; r++) {
                sh[tid + 256 * r] = gh[tid + 256 * r];
                sl[tid + 256 * r] = gl[tid + 256 * r];
            }
        }
        __syncthreads();
#pragma unroll
        for (int tt = 0; tt < 4; tt++) {
            int t = half * 4 + tt;
            f32x4 acc0 = (f32x4)(0.f), acc1 = (f32x4)(0.f);
#pragma unroll
            for (int ks = 0; ks < 4; ks++) {
                int fo = ((tt * 4 + ks) * 64 + lane) * 8;
                bf16x8 bh = *(const bf16x8*)&ldsW[0][fo];
                bf16x8 bl = *(const bf16x8*)&ldsW[1][fo];
                acc0 = __builtin_amdgcn_mfma_f32_16x16x32_bf16(A[0][ks][0], bh, acc0, 0, 0, 0);
                acc1 = __builtin_amdgcn_mfma_f32_16x16x32_bf16(A[1][ks][0], bh, acc1, 0, 0, 0);
                acc0 = __builtin_amdgcn_mfma_f32_16x16x32_bf16(A[0][ks][1], bh, acc0, 0, 0, 0);
                acc1 = __builtin_amdgcn_mfma_f32_16x16x32_bf16(A[1][ks][1], bh, acc1, 0, 0, 0);
                acc0 = __builtin_amdgcn_mfma_f32_16x16x32_bf16(A[0][ks][0], bl, acc0, 0, 0, 0);
                acc1 = __builtin_amdgcn_mfma_f32_16x16x32_bf16(A[1][ks][0], bl, acc1, 0, 0, 0);
            }
#pragma unroll
            for (int m = 0; m < 2; m++) {
                f32x4 a = m ? acc1 : acc0;
#pragma unroll
                for (int r = 0; r < 4; r++) {
                    int row = rowbase + m * 16 + q * 4 + r;
                    if (row < n) h[(size_t)row * GCN_DIM + t * 16 + ln] = f2bf(a[r]);
                }
            }
        }
    }
}

// Sliced aggregation: block = 16 nodes x one 32-feature slice (slice =
// blockIdx&3 -> XCD k sees only slice k%4 under round-robin dispatch).
// Wave = 4 nodes x 16 lanes x 2 feats. Unroll x8, 4 acc pairs.
// Outputs stored NON-TEMPORAL so their write-allocations don't evict the
// resident h-slice from this XCD's L2.
__global__ __launch_bounds__(256) void agg_kernel(
    const unsigned short* __restrict__ h,
    const unsigned int* __restrict__ edat,
    const int* __restrict__ offs,
    const float* __restrict__ dinv, const float* __restrict__ bias,
    unsigned short* __restrict__ xh_out,
    unsigned short* __restrict__ xl_out,
    float* __restrict__ fout, int n) {
    int tid = threadIdx.x;
    int wave = tid >> 6, lane = tid & 63;
    int sub = lane >> 4, ln = lane & 15;
    int slice = blockIdx.x & 3;
    int node = (blockIdx.x >> 2) * 16 + wave * 4 + sub;
    if (node >= n) return;
    int co = slice * 32 + ln * 2;  // this lane's 2 features
    float di = dinv[node];
    unsigned int sp = *(const unsigned int*)&h[((size_t)node << 7) + co];
    float ax0 = di * bflo(sp), ay0 = di * bfhi(sp);
    float ax1 = 0.f, ay1 = 0.f, ax2 = 0.f, ay2 = 0.f, ax3 = 0.f, ay3 = 0.f;
    int s = offs[node], e = offs[node + 1];
    int j = s;
    for (; j + 8 <= e; j += 8) {
        unsigned int v0 = edat[j], v1 = edat[j + 1], v2 = edat[j + 2], v3 = edat[j + 3];
        unsigned int v4 = edat[j + 4], v5 = edat[j + 5], v6 = edat[j + 6], v7 = edat[j + 7];
        unsigned int p0 = *(const unsigned int*)&h[((size_t)(v0 & 0xFFFFu) << 7) + co];
        unsigned int p1 = *(const unsigned int*)&h[((size_t)(v1 & 0xFFFFu) << 7) + co];
        unsigned int p2 = *(const unsigned int*)&h[((size_t)(v2 & 0xFFFFu) << 7) + co];
        unsigned int p3 = *(const unsigned int*)&h[((size_t)(v3 & 0xFFFFu) << 7) + co];
        unsigned int p4 = *(const unsigned int*)&h[((size_t)(v4 & 0xFFFFu) << 7) + co];
        unsigned int p5 = *(const unsigned int*)&h[((size_t)(v5 & 0xFFFFu) << 7) + co];
        unsigned int p6 = *(const unsigned int*)&h[((size_t)(v6 & 0xFFFFu) << 7) + co];
        unsigned int p7 = *(const unsigned int*)&h[((size_t)(v7 & 0xFFFFu) << 7) + co];
        float w0 = rsqrtf((float)(v0 >> 16) + 1.0f);
        float w1 = rsqrtf((float)(v1 >> 16) + 1.0f);
        float w2 = rsqrtf((float)(v2 >> 16) + 1.0f);
        float w3 = rsqrtf((float)(v3 >> 16) + 1.0f);
        float w4 = rsqrtf((float)(v4 >> 16) + 1.0f);
        float w5 = rsqrtf((float)(v5 >> 16) + 1.0f);
        float w6 = rsqrtf((float)(v6 >> 16) + 1.0f);
        float w7 = rsqrtf((float)(v7 >> 16) + 1.0f);
        ax0 = fmaf(w0, bflo(p0), ax0); ay0 = fmaf(w0, bfhi(p0), ay0);
        ax1 = fmaf(w1, bflo(p1), ax1); ay1 = fmaf(w1, bfhi(p1), ay1);
        ax2 = fmaf(w2, bflo(p2), ax2); ay2 = fmaf(w2, bfhi(p2), ay2);
        ax3 = fmaf(w3, bflo(p3), ax3); ay3 = fmaf(w3, bfhi(p3), ay3);
        ax0 = fmaf(w4, bflo(p4), ax0); ay0 = fmaf(w4, bfhi(p4), ay0);
        ax1 = fmaf(w5, bflo(p5), ax1); ay1 = fmaf(w5, bfhi(p5), ay1);
        ax2 = fmaf(w6, bflo(p6), ax2); ay2 = fmaf(w6, bfhi(p6), ay2);
        ax3 = fmaf(w7, bflo(p7), ax3); ay3 = fmaf(w7, bfhi(p7), ay3);
    }
    for (; j + 4 <= e; j += 4) {
        unsigned int v0 = edat[j], v1 = edat[j + 1], v2 = edat[j + 2], v3 = edat[j + 3];
        unsigned int p0 = *(const unsigned int*)&h[((size_t)(v0 & 0xFFFFu) << 7) + co];
        unsigned int p1 = *(const unsigned int*)&h[((size_t)(v1 & 0xFFFFu) << 7) + co];
        unsigned int p2 = *(const unsigned int*)&h[((size_t)(v2 & 0xFFFFu) << 7) + co];
        unsigned int p3 = *(const unsigned int*)&h[((size_t)(v3 & 0xFFFFu) << 7) + co];
        float w0 = rsqrtf((float)(v0 >> 16) + 1.0f);
        float w1 = rsqrtf((float)(v1 >> 16) + 1.0f);
        float w2 = rsqrtf((float)(v2 >> 16) + 1.0f);
        float w3 = rsqrtf((float)(v3 >> 16) + 1.0f);
        ax0 = fmaf(w0, bflo(p0), ax0); ay0 = fmaf(w0, bfhi(p0), ay0);
        ax1 = fmaf(w1, bflo(p1), ax1); ay1 = fmaf(w1, bfhi(p1), ay1);
        ax2 = fmaf(w2, bflo(p2), ax2); ay2 = fmaf(w2, bfhi(p2), ay2);
        ax3 = fmaf(w3, bflo(p3), ax3); ay3 = fmaf(w3, bfhi(p3), ay3);
    }
    for (; j < e; j++) {
        unsigned int v0 = edat[j];
        unsigned int p0 = *(const unsigned int*)&h[((size_t)(v0 & 0xFFFFu) << 7) + co];
        float w0 = rsqrtf((float)(v0 >> 16) + 1.0f);
        ax0 = fmaf(w0, bflo(p0), ax0);
        ay0 = fmaf(w0, bfhi(p0), ay0);
    }
    float ax = (ax0 + ax1) + (ax2 + ax3);
    float ay = (ay0 + ay1) + (ay2 + ay3);
    float2 b = *(const float2*)&bias[co];
    float rx = fmaxf(fmaf(di, ax, b.x), 0.f);
    float ry = fmaxf(fmaf(di, ay, b.y), 0.f);
    if (fout) {
        unsigned long long pv = (unsigned long long)__float_as_uint(rx) |
                                ((unsigned long long)__float_as_uint(ry) << 32);
        __builtin_nontemporal_store(pv, (unsigned long long*)&fout[((size_t)node << 7) + co]);
    } else {
        unsigned short hx = f2bf(rx), hy = f2bf(ry);
        unsigned int hp = (unsigned int)hx | ((unsigned int)hy << 16);
        unsigned short lx = f2bf(rx - bf2f(hx)), ly = f2bf(ry - bf2f(hy));
        unsigned int lp = (unsigned int)lx | ((unsigned int)ly << 16);
        __builtin_nontemporal_store(hp, (unsigned int*)&xh_out[((size_t)node << 7) + co]);
        __builtin_nontemporal_store(lp, (unsigned int*)&xl_out[((size_t)node << 7) + co]);
    }
}

extern "C" void kernel_launch(void* const* d_in, const int* in_sizes, int n_in,
                              void* d_out, int out_size, void* d_ws, size_t ws_size,
                              hipStream_t stream) {
    const float* x0    = (const float*)d_in[0];
    const int*   edges = (const int*)d_in[1];   // [2, E] int32: src then dst
    const float* Wall  = (const float*)d_in[2]; // [L, 128, 128]
    const float* Ball  = (const float*)d_in[3]; // [L, 128]
    float* out = (float*)d_out;

    const int n = in_sizes[0] / GCN_DIM;              // 50000
    const int E = in_sizes[1] / 2;                    // 800000
    const int L = in_sizes[2] / (GCN_DIM * GCN_DIM);  // 5

    // workspace layout
    int*   cnt    = (int*)d_ws;                        // n
    float* dinv   = (float*)(cnt + n);                 // n
    int*   offs   = (int*)(dinv + n);                  // n+16
    int*   bsum   = offs + n + 16;                     // 64
    int*   rank   = bsum + 64;                         // E
    unsigned int* edat = (unsigned int*)(rank + E);    // E (4B each)
    unsigned short* h   = (unsigned short*)(edat + E); // n*128 bf16
    unsigned short* xh  = h  + (size_t)n * GCN_DIM;    // n*128 bf16
    unsigned short* xl  = xh + (size_t)n * GCN_DIM;    // n*128 bf16
    unsigned short* Wfh = xl + (size_t)n * GCN_DIM;    // L*16384 bf16 frag-order
    unsigned short* Wfl = Wfh + (size_t)L * GCN_DIM * GCN_DIM;

    const int* src = edges;
    const int* dst = edges + E;

    int nb_n = (n + 255) / 256;
    int nb_e = (E + 255) / 256;
    int nb_scan = (n + 1023) / 1024;

    init_kernel<<<nb_n, 256, 0, stream>>>(cnt, n);
    count_kernel<<<nb_e, 256, 0, stream>>>(dst, cnt, rank, E);
    scan_part_kernel<<<nb_scan, 256, 0, stream>>>(cnt, offs, bsum, n);
    scan_top_kernel<<<1, 256, 0, stream>>>(bsum, nb_scan);
    scan_add_kernel<<<nb_n, 256, 0, stream>>>(offs, bsum, cnt, dinv, n, E);
    fill_kernel<<<nb_e, 256, 0, stream>>>(src, dst, cnt, rank, offs, edat, E);

    int xtotal = n * GCN_DIM;
    split_x_kernel<<<(xtotal / 4 + 255) / 256, 256, 0, stream>>>(x0, xh, xl, xtotal);
    int wtotal = L * GCN_DIM * GCN_DIM;
    wsplit_kernel<<<(wtotal + 255) / 256, 256, 0, stream>>>(Wall, Wfh, Wfl, wtotal);

    int gemm_blocks = (n + 127) / 128;
    int agg_blocks  = ((n + 15) / 16) * 4;  // 16 nodes x 4 slices per block

    for (int l = 0; l < L; l++) {
        gemm_mfma_kernel<<<gemm_blocks, 256, 0, stream>>>(
            xh, xl, Wfh + (size_t)l * GCN_DIM * GCN_DIM, Wfl + (size_t)l * GCN_DIM * GCN_DIM, h, n);
        agg_kernel<<<agg_blocks, 256, 0, stream>>>(
            h, edat, offs, dinv, Ball + (size_t)l * GCN_DIM,
            xh, xl, (l == L - 1) ? out : nullptr, n);
    }
}